// Round 6
// baseline (223.415 us; speedup 1.0000x reference)
//
#include <hip/hip_runtime.h>

#define DIM   1024
#define NQKV  3072
#define SEQ   2048
#define HEADS 16
#define DHEAD 64
#define M_TOT 4096   // batch(2) * seq(2048)

typedef __bf16 bf16;
typedef __bf16 bf16x8 __attribute__((ext_vector_type(8)));
typedef float  f32x4  __attribute__((ext_vector_type(4)));

typedef const __attribute__((address_space(1))) unsigned int gu32;
typedef __attribute__((address_space(3))) unsigned int su32;

static __device__ __forceinline__ unsigned short f2b(float f) {
    bf16 h = (bf16)f;
    return __builtin_bit_cast(unsigned short, h);
}

// ---------------- kernel 1: fused prep (cast x -> bf16 | transpose+scale W) ----------------
// R8: transpose in 64x64 tiles, float4 global reads, uint4 global writes.
#define CAST_BLOCKS (M_TOT * DIM / (256 * 4))
#define TR_NB (NQKV / 64)   // 48
__global__ void prep_kernel(const float* __restrict__ x,
                            unsigned short* __restrict__ xb,
                            const float* __restrict__ W,
                            unsigned short* __restrict__ Wt) {
    __shared__ float tile[64][65];   // [n_local][k_local], padded
    const int id  = blockIdx.x;
    const int tid = threadIdx.x;
    if (id < CAST_BLOCKS) {
        int i = (id * 256 + tid) * 4;
        float4 v = *(const float4*)(x + i);
        ushort4 o;
        o.x = f2b(v.x); o.y = f2b(v.y); o.z = f2b(v.z); o.w = f2b(v.w);
        *(ushort4*)(xb + i) = o;
    } else {
        int t  = id - CAST_BLOCKS;
        int nb = t % TR_NB;
        int kb = t / TR_NB;          // 0..15
        #pragma unroll
        for (int p = 0; p < 4; p++) {
            int kl = p * 16 + (tid >> 4);        // 0..63
            int nl = (tid & 15) * 4;             // 0..60
            float4 v = *(const float4*)&W[(size_t)(kb * 64 + kl) * NQKV + nb * 64 + nl];
            tile[nl + 0][kl] = v.x;
            tile[nl + 1][kl] = v.y;
            tile[nl + 2][kl] = v.z;
            tile[nl + 3][kl] = v.w;
        }
        __syncthreads();
        #pragma unroll
        for (int p = 0; p < 2; p++) {
            int nl = p * 32 + (tid >> 3);        // 0..63
            int k8 = (tid & 7) * 8;              // 0..56
            int n  = nb * 64 + nl;
            float s = (n < 1024) ? 0.18033688f : 1.0f;   // 0.125 * log2(e)
            float4 a = *(const float4*)&tile[nl][k8];
            float4 b = *(const float4*)&tile[nl][k8 + 4];
            ushort4 o0, o1;
            o0.x = f2b(a.x * s); o0.y = f2b(a.y * s); o0.z = f2b(a.z * s); o0.w = f2b(a.w * s);
            o1.x = f2b(b.x * s); o1.y = f2b(b.y * s); o1.z = f2b(b.z * s); o1.w = f2b(b.w * s);
            uint4 pk;
            pk.x = ((unsigned)o0.y << 16) | o0.x;
            pk.y = ((unsigned)o0.w << 16) | o0.z;
            pk.z = ((unsigned)o1.y << 16) | o1.x;
            pk.w = ((unsigned)o1.w << 16) | o1.z;
            *(uint4*)&Wt[(size_t)n * DIM + kb * 64 + k8] = pk;
        }
    }
}

// ---------------- kernel 2: QKV GEMM, LDS-restaged coalesced epilogue ----------------
#define LDC 136
__global__ __launch_bounds__(256) void qkv_gemm_kernel(
    const unsigned short* __restrict__ A,
    const unsigned short* __restrict__ Bt,
    unsigned short* __restrict__ Qw,
    unsigned short* __restrict__ Kw,
    unsigned short* __restrict__ Vtw)
{
    __shared__ __align__(16) unsigned char smem[128 * LDC * 2];   // 34816 B
    unsigned short* As = (unsigned short*)smem;
    unsigned short* Bs = (unsigned short*)(smem + 16384);
    unsigned short* Cs = (unsigned short*)smem;

    const int tid  = threadIdx.x;
    const int m0   = blockIdx.y * 128;
    const int n0   = blockIdx.x * 128;
    const int w    = tid >> 6;
    const int lane = tid & 63;
    const int l16  = lane & 15;
    const int quad = lane >> 4;
    const int wm   = (w >> 1) * 64;
    const int wn   = (w & 1) * 64;
    const int srow = lane >> 3;
    const int scol = (lane & 7) * 8;

    f32x4 acc[4][4];
    const f32x4 fzero = {0.f, 0.f, 0.f, 0.f};
    for (int i = 0; i < 4; i++)
        for (int j = 0; j < 4; j++) acc[i][j] = fzero;

    const unsigned short* Ag = A  + (size_t)(m0 + w * 32 + srow) * DIM + scol;
    const unsigned short* Bg = Bt + (size_t)(n0 + w * 32 + srow) * DIM + scol;

    for (int kt = 0; kt < DIM; kt += 64) {
        #pragma unroll
        for (int j = 0; j < 4; j++) {
            __builtin_amdgcn_global_load_lds((gu32*)(Ag + kt + (size_t)j * 8 * DIM),
                                             (su32*)&As[(w * 32 + j * 8) * 64], 16, 0, 0);
            __builtin_amdgcn_global_load_lds((gu32*)(Bg + kt + (size_t)j * 8 * DIM),
                                             (su32*)&Bs[(w * 32 + j * 8) * 64], 16, 0, 0);
        }
        __syncthreads();
        #pragma unroll
        for (int s = 0; s < 2; s++) {
            bf16x8 af[4], bfr[4];
            #pragma unroll
            for (int i = 0; i < 4; i++) {
                af[i]  = *(const bf16x8*)(&As[(wm + i * 16 + l16) * 64 + s * 32 + quad * 8]);
                bfr[i] = *(const bf16x8*)(&Bs[(wn + i * 16 + l16) * 64 + s * 32 + quad * 8]);
            }
            #pragma unroll
            for (int i = 0; i < 4; i++)
                #pragma unroll
                for (int j = 0; j < 4; j++)
                    acc[i][j] = __builtin_amdgcn_mfma_f32_16x16x32_bf16(af[i], bfr[j], acc[i][j], 0, 0, 0);
        }
        __syncthreads();
    }

    const int part = n0 >> 10;
    const int h0   = (n0 & 1023) >> 6;
    const int b    = m0 >> 11;
    const int np0  = m0 & 2047;

    if (part < 2) {
        #pragma unroll
        for (int i = 0; i < 4; i++)
            #pragma unroll
            for (int j = 0; j < 4; j++)
                #pragma unroll
                for (int r = 0; r < 4; r++)
                    Cs[(wm + i * 16 + quad * 4 + r) * LDC + wn + j * 16 + l16] = f2b(acc[i][j][r]);
        __syncthreads();
        unsigned short* dst = (part == 0) ? Qw : Kw;
        #pragma unroll
        for (int pass = 0; pass < 8; pass++) {
            int mi = pass * 16 + (tid >> 4);
            int ci = (tid & 15) * 8;
            uint4 v = *(const uint4*)&Cs[mi * LDC + ci];
            int bh = b * HEADS + h0 + (ci >> 6);
            *(uint4*)&dst[((size_t)bh * SEQ + np0 + mi) * DHEAD + (ci & 63)] = v;
        }
    } else {
        #pragma unroll
        for (int i = 0; i < 4; i++)
            #pragma unroll
            for (int j = 0; j < 4; j++) {
                ushort4 pk;
                pk.x = f2b(acc[i][j][0]); pk.y = f2b(acc[i][j][1]);
                pk.z = f2b(acc[i][j][2]); pk.w = f2b(acc[i][j][3]);
                *(ushort4*)&Cs[(wn + j * 16 + l16) * LDC + wm + i * 16 + quad * 4] = pk;
            }
        __syncthreads();
        #pragma unroll
        for (int pass = 0; pass < 8; pass++) {
            int ci = pass * 16 + (tid >> 4);
            int mi = (tid & 15) * 8;
            uint4 v = *(const uint4*)&Cs[ci * LDC + mi];
            int bh = b * HEADS + h0 + (ci >> 6);
            *(uint4*)&Vtw[((size_t)bh * DHEAD + (ci & 63)) * SEQ + np0 + mi] = v;
        }
    }
}

// ---------------- kernel 3: flash attention + residual ----------------
// R12: co-residency model from R2-R5 data: blocks/CU = floor(~81920 /
// LDS_Block_Size) -- 43008 was over the half-pool line (1 block/CU, occ 9.7%);
// 36864 gave 2 blocks (occ 18.8%). Keep the R10/R11 work-split (4 waves =
// 2 q-groups x 2 key-halves; 4 indep qh dep-chains/wave; each kf/vf LDS read
// feeds 4 MFMAs) but shrink LDS to 34816 B: LDK 72->68 (136B rows, bank-start
// (2*l16+16s+4quad)%32 -> balanced, same structural 8 acc/bank as LDK=72) and
// a 2-pass epilogue reduction through a 20480B scratch region.
#define LDK 68
#define TILE_E (64 * LDK)       // ushorts per staged tile (8704 B)
#define KT 16                   // key tiles per key-half
__global__ __launch_bounds__(256) void attn_kernel(
    const unsigned short* __restrict__ Qw,
    const unsigned short* __restrict__ Kw,
    const unsigned short* __restrict__ Vtw,
    const float* __restrict__ x,
    float* __restrict__ out)
{
    __shared__ __align__(16) unsigned char smem[TILE_E * 4 * 2];   // 34816 B
    unsigned short* Ks = (unsigned short*)smem;                    // [pair][64][LDK]
    unsigned short* Vs = (unsigned short*)(smem + TILE_E * 2 * 2); // [pair] V^T [d][key]
    float* scratch = (float*)smem;                                 // epilogue reuse (20480 B)

    const int id  = blockIdx.x;
    const int qt  = id >> 5;                                // 0..15 (128-query tiles)
    const int bh  = ((id & 7) << 2) | ((id >> 3) & 3);      // 4 bh per XCD
    const int tid = threadIdx.x;
    const int w   = tid >> 6, lane = tid & 63;
    const int l16 = lane & 15, quad = lane >> 4;
    const int g   = w & 1;      // q-group (64 queries)
    const int p   = w >> 1;     // key-half (1024 keys)

    const unsigned short* Qb = Qw + ((size_t)bh * SEQ + qt * 128 + g * 64 + l16) * DHEAD;
    bf16x8 qf[4][2];
    #pragma unroll
    for (int qh = 0; qh < 4; qh++) {
        qf[qh][0] = *(const bf16x8*)(Qb + qh * 16 * DHEAD + quad * 8);
        qf[qh][1] = *(const bf16x8*)(Qb + qh * 16 * DHEAD + 32 + quad * 8);
    }

    bf16x8 ones;
    #pragma unroll
    for (int j = 0; j < 8; j++) ones[j] = (bf16)1.0f;

    f32x4 o[4][4], dsum[4];
    const f32x4 fzero = {0.f, 0.f, 0.f, 0.f};
    #pragma unroll
    for (int qh = 0; qh < 4; qh++) {
        #pragma unroll
        for (int d = 0; d < 4; d++) o[qh][d] = fzero;
        dsum[qh] = fzero;
    }

    const unsigned short* Kg = Kw  + (size_t)bh * SEQ * DHEAD;
    const unsigned short* Vg = Vtw + (size_t)bh * DHEAD * SEQ;

    const int r0 = tid >> 3, c0 = (tid & 7) * 8;
    // physical Ks row for logical key r0: p = ki*16 + l16 (read-permutation inverse)
    const int pr0 = ((r0 >> 2) & 1) * 16 + ((r0 >> 3) & 3) * 4 + (r0 & 3);

    // prologue: tile 0 of both key-halves -> regs
    uint4 k00 = *(const uint4*)(Kg + (size_t)r0 * DHEAD + c0);
    uint4 k01 = *(const uint4*)(Kg + (size_t)(r0 + 32) * DHEAD + c0);
    uint4 k10 = *(const uint4*)(Kg + (size_t)(1024 + r0) * DHEAD + c0);
    uint4 k11 = *(const uint4*)(Kg + (size_t)(1024 + r0 + 32) * DHEAD + c0);
    uint4 v00 = *(const uint4*)(Vg + (size_t)r0 * SEQ + c0);
    uint4 v01 = *(const uint4*)(Vg + (size_t)(r0 + 32) * SEQ + c0);
    uint4 v10 = *(const uint4*)(Vg + (size_t)r0 * SEQ + 1024 + c0);
    uint4 v11 = *(const uint4*)(Vg + (size_t)(r0 + 32) * SEQ + 1024 + c0);

    for (int t = 0; t < KT; t++) {
        __syncthreads();   // readers of tile t-1 done
        *(uint4*)&Ks[0 * TILE_E + pr0 * LDK + c0]        = k00;
        *(uint4*)&Ks[0 * TILE_E + (pr0 + 32) * LDK + c0] = k01;
        *(uint4*)&Ks[1 * TILE_E + pr0 * LDK + c0]        = k10;
        *(uint4*)&Ks[1 * TILE_E + (pr0 + 32) * LDK + c0] = k11;
        *(uint4*)&Vs[0 * TILE_E + r0 * LDK + c0]         = v00;
        *(uint4*)&Vs[0 * TILE_E + (r0 + 32) * LDK + c0]  = v01;
        *(uint4*)&Vs[1 * TILE_E + r0 * LDK + c0]         = v10;
        *(uint4*)&Vs[1 * TILE_E + (r0 + 32) * LDK + c0]  = v11;
        __syncthreads();   // staging visible
        // issue global loads of tile t+1 (latency hides under this tile's compute)
        int kvn = ((t + 1) & (KT - 1)) * 64;
        k00 = *(const uint4*)(Kg + (size_t)(kvn + r0) * DHEAD + c0);
        k01 = *(const uint4*)(Kg + (size_t)(kvn + r0 + 32) * DHEAD + c0);
        k10 = *(const uint4*)(Kg + (size_t)(1024 + kvn + r0) * DHEAD + c0);
        k11 = *(const uint4*)(Kg + (size_t)(1024 + kvn + r0 + 32) * DHEAD + c0);
        v00 = *(const uint4*)(Vg + (size_t)r0 * SEQ + kvn + c0);
        v01 = *(const uint4*)(Vg + (size_t)(r0 + 32) * SEQ + kvn + c0);
        v10 = *(const uint4*)(Vg + (size_t)r0 * SEQ + 1024 + kvn + c0);
        v11 = *(const uint4*)(Vg + (size_t)(r0 + 32) * SEQ + 1024 + kvn + c0);

        // S^T = K_perm · Q^T for 4 query-sixteens; each kf read feeds 4 MFMAs
        const unsigned short* Kb = Ks + (size_t)p * TILE_E;
        f32x4 sacc[4][4];   // [qh][ki]
        #pragma unroll
        for (int qh = 0; qh < 4; qh++)
            #pragma unroll
            for (int ki = 0; ki < 4; ki++) sacc[qh][ki] = fzero;
        #pragma unroll
        for (int s = 0; s < 2; s++)
            #pragma unroll
            for (int ki = 0; ki < 4; ki++) {
                bf16x8 kf = *(const bf16x8*)(&Kb[(ki * 16 + l16) * LDK + s * 32 + quad * 8]);
                #pragma unroll
                for (int qh = 0; qh < 4; qh++)
                    sacc[qh][ki] = __builtin_amdgcn_mfma_f32_16x16x32_bf16(kf, qf[qh][s], sacc[qh][ki], 0, 0, 0);
            }

        // p = exp2(s); C-regs are the PV A-frags; denominator via ones-MFMA
        bf16x8 pf[4][2];
        #pragma unroll
        for (int qh = 0; qh < 4; qh++)
            #pragma unroll
            for (int s = 0; s < 2; s++)
                #pragma unroll
                for (int half = 0; half < 2; half++) {
                    int ki = 2 * s + half;
                    #pragma unroll
                    for (int r = 0; r < 4; r++)
                        pf[qh][s][half * 4 + r] = (bf16)__builtin_amdgcn_exp2f(sacc[qh][ki][r]);
                }

        const unsigned short* Vb = Vs + (size_t)p * TILE_E;
        #pragma unroll
        for (int s = 0; s < 2; s++) {
            #pragma unroll
            for (int qh = 0; qh < 4; qh++)
                dsum[qh] = __builtin_amdgcn_mfma_f32_16x16x32_bf16(pf[qh][s], ones, dsum[qh], 0, 0, 0);
            #pragma unroll
            for (int d = 0; d < 4; d++) {
                bf16x8 vf = *(const bf16x8*)(&Vb[(d * 16 + l16) * LDK + s * 32 + quad * 8]);
                #pragma unroll
                for (int qh = 0; qh < 4; qh++)
                    o[qh][d] = __builtin_amdgcn_mfma_f32_16x16x32_bf16(pf[qh][s], vf, o[qh][d], 0, 0, 0);
            }
        }
    }

    // ---- combine the two key-half partials: 2 passes through 20480B scratch ----
    __syncthreads();   // all waves done reading K/V LDS
    #pragma unroll
    for (int pass = 0; pass < 2; pass++) {
        if (pass) __syncthreads();          // pass-0 readers done before overwrite
        if (w >= 2) {                        // key-half 1 writes its partials
            float* sc = scratch + ((size_t)((w - 2) * 64 + lane)) * 40;
            #pragma unroll
            for (int q2 = 0; q2 < 2; q2++) {
                int qh = pass * 2 + q2;
                #pragma unroll
                for (int di = 0; di < 4; di++)
                    *(f32x4*)(sc + q2 * 20 + di * 4) = o[qh][di];
                *(f32x4*)(sc + q2 * 20 + 16) = dsum[qh];
            }
        }
        __syncthreads();
        if (w < 2) {
            float* sc = scratch + ((size_t)(w * 64 + lane)) * 40;
            #pragma unroll
            for (int q2 = 0; q2 < 2; q2++) {
                int qh = pass * 2 + q2;
                #pragma unroll
                for (int di = 0; di < 4; di++)
                    o[qh][di] += *(const f32x4*)(sc + q2 * 20 + di * 4);
                dsum[qh] += *(const f32x4*)(sc + q2 * 20 + 16);
            }
        }
    }

    if (w < 2) {
        const int b = bh >> 4, h = bh & 15;
        #pragma unroll
        for (int qh = 0; qh < 4; qh++) {
            float lr[4];
            #pragma unroll
            for (int r = 0; r < 4; r++) lr[r] = __builtin_amdgcn_rcpf(dsum[qh][r]);
            #pragma unroll
            for (int di = 0; di < 4; di++)
                #pragma unroll
                for (int r = 0; r < 4; r++) {
                    int np  = qt * 128 + g * 64 + qh * 16 + quad * 4 + r;
                    int col = h * 64 + di * 16 + l16;
                    size_t gidx = ((size_t)(b * SEQ + np)) * DIM + col;
                    out[gidx] = o[qh][di][r] * lr[r] + x[gidx];
                }
        }
    }
}

extern "C" void kernel_launch(void* const* d_in, const int* in_sizes, int n_in,
                              void* d_out, int out_size, void* d_ws, size_t ws_size,
                              hipStream_t stream) {
    const float* x  = (const float*)d_in[0];   // [2,2048,1024]
    const float* Wq = (const float*)d_in[1];   // [1024,3072]
    float* out = (float*)d_out;

    unsigned short* xb = (unsigned short*)d_ws;                  // [4096][1024]
    unsigned short* Wt = xb + (size_t)M_TOT * DIM;               // [3072][1024]
    unsigned short* Qw = Wt + (size_t)NQKV * DIM;                // [32][2048][64]
    unsigned short* Kw = Qw + (size_t)32 * SEQ * DHEAD;          // [32][2048][64]
    unsigned short* Vt = Kw + (size_t)32 * SEQ * DHEAD;          // [32][64][2048]

    prep_kernel<<<CAST_BLOCKS + TR_NB * (DIM / 64), 256, 0, stream>>>(x, xb, Wq, Wt);
    qkv_gemm_kernel<<<dim3(NQKV / 128, M_TOT / 128), 256, 0, stream>>>(xb, Wt, Qw, Kw, Vt);
    attn_kernel<<<(SEQ / 128) * 32, 256, 0, stream>>>(Qw, Kw, Vt, x, out);
}

// Round 7
// 160.039 us; speedup vs baseline: 1.3960x; 1.3960x over previous
//
#include <hip/hip_runtime.h>

#define DIM   1024
#define NQKV  3072
#define SEQ   2048
#define HEADS 16
#define DHEAD 64
#define M_TOT 4096   // batch(2) * seq(2048)

typedef __bf16 bf16;
typedef __bf16 bf16x8 __attribute__((ext_vector_type(8)));
typedef float  f32x4  __attribute__((ext_vector_type(4)));

typedef const __attribute__((address_space(1))) unsigned int gu32;
typedef __attribute__((address_space(3))) unsigned int su32;

static __device__ __forceinline__ unsigned short f2b(float f) {
    bf16 h = (bf16)f;
    return __builtin_bit_cast(unsigned short, h);
}

// ---------------- kernel 1: fused prep (cast x -> bf16 | transpose+scale W) ----------------
// R8: transpose in 64x64 tiles, float4 global reads, uint4 global writes.
#define CAST_BLOCKS (M_TOT * DIM / (256 * 4))
#define TR_NB (NQKV / 64)   // 48
__global__ void prep_kernel(const float* __restrict__ x,
                            unsigned short* __restrict__ xb,
                            const float* __restrict__ W,
                            unsigned short* __restrict__ Wt) {
    __shared__ float tile[64][65];   // [n_local][k_local], padded
    const int id  = blockIdx.x;
    const int tid = threadIdx.x;
    if (id < CAST_BLOCKS) {
        int i = (id * 256 + tid) * 4;
        float4 v = *(const float4*)(x + i);
        ushort4 o;
        o.x = f2b(v.x); o.y = f2b(v.y); o.z = f2b(v.z); o.w = f2b(v.w);
        *(ushort4*)(xb + i) = o;
    } else {
        int t  = id - CAST_BLOCKS;
        int nb = t % TR_NB;
        int kb = t / TR_NB;          // 0..15
        #pragma unroll
        for (int p = 0; p < 4; p++) {
            int kl = p * 16 + (tid >> 4);        // 0..63
            int nl = (tid & 15) * 4;             // 0..60
            float4 v = *(const float4*)&W[(size_t)(kb * 64 + kl) * NQKV + nb * 64 + nl];
            tile[nl + 0][kl] = v.x;
            tile[nl + 1][kl] = v.y;
            tile[nl + 2][kl] = v.z;
            tile[nl + 3][kl] = v.w;
        }
        __syncthreads();
        #pragma unroll
        for (int p = 0; p < 2; p++) {
            int nl = p * 32 + (tid >> 3);        // 0..63
            int k8 = (tid & 7) * 8;              // 0..56
            int n  = nb * 64 + nl;
            float s = (n < 1024) ? 0.18033688f : 1.0f;   // 0.125 * log2(e)
            float4 a = *(const float4*)&tile[nl][k8];
            float4 b = *(const float4*)&tile[nl][k8 + 4];
            ushort4 o0, o1;
            o0.x = f2b(a.x * s); o0.y = f2b(a.y * s); o0.z = f2b(a.z * s); o0.w = f2b(a.w * s);
            o1.x = f2b(b.x * s); o1.y = f2b(b.y * s); o1.z = f2b(b.z * s); o1.w = f2b(b.w * s);
            uint4 pk;
            pk.x = ((unsigned)o0.y << 16) | o0.x;
            pk.y = ((unsigned)o0.w << 16) | o0.z;
            pk.z = ((unsigned)o1.y << 16) | o1.x;
            pk.w = ((unsigned)o1.w << 16) | o1.z;
            *(uint4*)&Wt[(size_t)n * DIM + kb * 64 + k8] = pk;
        }
    }
}

// ---------------- kernel 2: QKV GEMM, LDS-restaged coalesced epilogue ----------------
#define LDC 136
__global__ __launch_bounds__(256) void qkv_gemm_kernel(
    const unsigned short* __restrict__ A,
    const unsigned short* __restrict__ Bt,
    unsigned short* __restrict__ Qw,
    unsigned short* __restrict__ Kw,
    unsigned short* __restrict__ Vtw)
{
    __shared__ __align__(16) unsigned char smem[128 * LDC * 2];   // 34816 B
    unsigned short* As = (unsigned short*)smem;
    unsigned short* Bs = (unsigned short*)(smem + 16384);
    unsigned short* Cs = (unsigned short*)smem;

    const int tid  = threadIdx.x;
    const int m0   = blockIdx.y * 128;
    const int n0   = blockIdx.x * 128;
    const int w    = tid >> 6;
    const int lane = tid & 63;
    const int l16  = lane & 15;
    const int quad = lane >> 4;
    const int wm   = (w >> 1) * 64;
    const int wn   = (w & 1) * 64;
    const int srow = lane >> 3;
    const int scol = (lane & 7) * 8;

    f32x4 acc[4][4];
    const f32x4 fzero = {0.f, 0.f, 0.f, 0.f};
    for (int i = 0; i < 4; i++)
        for (int j = 0; j < 4; j++) acc[i][j] = fzero;

    const unsigned short* Ag = A  + (size_t)(m0 + w * 32 + srow) * DIM + scol;
    const unsigned short* Bg = Bt + (size_t)(n0 + w * 32 + srow) * DIM + scol;

    for (int kt = 0; kt < DIM; kt += 64) {
        #pragma unroll
        for (int j = 0; j < 4; j++) {
            __builtin_amdgcn_global_load_lds((gu32*)(Ag + kt + (size_t)j * 8 * DIM),
                                             (su32*)&As[(w * 32 + j * 8) * 64], 16, 0, 0);
            __builtin_amdgcn_global_load_lds((gu32*)(Bg + kt + (size_t)j * 8 * DIM),
                                             (su32*)&Bs[(w * 32 + j * 8) * 64], 16, 0, 0);
        }
        __syncthreads();
        #pragma unroll
        for (int s = 0; s < 2; s++) {
            bf16x8 af[4], bfr[4];
            #pragma unroll
            for (int i = 0; i < 4; i++) {
                af[i]  = *(const bf16x8*)(&As[(wm + i * 16 + l16) * 64 + s * 32 + quad * 8]);
                bfr[i] = *(const bf16x8*)(&Bs[(wn + i * 16 + l16) * 64 + s * 32 + quad * 8]);
            }
            #pragma unroll
            for (int i = 0; i < 4; i++)
                #pragma unroll
                for (int j = 0; j < 4; j++)
                    acc[i][j] = __builtin_amdgcn_mfma_f32_16x16x32_bf16(af[i], bfr[j], acc[i][j], 0, 0, 0);
        }
        __syncthreads();
    }

    const int part = n0 >> 10;
    const int h0   = (n0 & 1023) >> 6;
    const int b    = m0 >> 11;
    const int np0  = m0 & 2047;

    if (part < 2) {
        #pragma unroll
        for (int i = 0; i < 4; i++)
            #pragma unroll
            for (int j = 0; j < 4; j++)
                #pragma unroll
                for (int r = 0; r < 4; r++)
                    Cs[(wm + i * 16 + quad * 4 + r) * LDC + wn + j * 16 + l16] = f2b(acc[i][j][r]);
        __syncthreads();
        unsigned short* dst = (part == 0) ? Qw : Kw;
        #pragma unroll
        for (int pass = 0; pass < 8; pass++) {
            int mi = pass * 16 + (tid >> 4);
            int ci = (tid & 15) * 8;
            uint4 v = *(const uint4*)&Cs[mi * LDC + ci];
            int bh = b * HEADS + h0 + (ci >> 6);
            *(uint4*)&dst[((size_t)bh * SEQ + np0 + mi) * DHEAD + (ci & 63)] = v;
        }
    } else {
        #pragma unroll
        for (int i = 0; i < 4; i++)
            #pragma unroll
            for (int j = 0; j < 4; j++) {
                ushort4 pk;
                pk.x = f2b(acc[i][j][0]); pk.y = f2b(acc[i][j][1]);
                pk.z = f2b(acc[i][j][2]); pk.w = f2b(acc[i][j][3]);
                *(ushort4*)&Cs[(wn + j * 16 + l16) * LDC + wm + i * 16 + quad * 4] = pk;
            }
        __syncthreads();
        #pragma unroll
        for (int pass = 0; pass < 8; pass++) {
            int ci = pass * 16 + (tid >> 4);
            int mi = (tid & 15) * 8;
            uint4 v = *(const uint4*)&Cs[ci * LDC + mi];
            int bh = b * HEADS + h0 + (ci >> 6);
            *(uint4*)&Vtw[((size_t)bh * DHEAD + (ci & 63)) * SEQ + np0 + mi] = v;
        }
    }
}

// ---------------- kernel 3: flash attention + residual ----------------
// R13. Lessons burned in from R4-R6 counters:
//  (a) VGPR>128 kills co-residency (R9 vgpr68 -> occ 18.8%; R10-12 vgpr148 ->
//      ~10% regardless of LDS 73728/43008/34816). Cap at 128.
//  (b) LDS rows must be 16B-aligned or b128 ops get split (R12: LDK=68 ->
//      1.7x slower with conflicts ~0). LDK=64 here.
//  (c) Conflict counter is real, not structural: 2^21..2^23 in R1-R5 were the
//      144B-stride ds_write_b128 staging writes; reads were even.
// Structure: 512-thread blocks (8 waves = 4 q-groups x 2 key-halves), grid 512
// -> 2 blocks/CU = 16 waves/CU (2x R9 residency; R3 showed latency-bound).
// K/V staged via global_load_lds (linear LDS dest, per-lane PRE-SWIZZLED +
// row-permuted global source): XOR swizzle col16 ^= row&7 makes the column-
// sliced b128 reads perfectly even; DMA writes are linear (conflict-free);
// no staging VGPRs. Single-buffered 32768B LDS; key-half partials combined
// through LDS scratch (2 passes), division after the sum.
#define KT 16                   // key tiles per key-half
__global__ __launch_bounds__(512, 4) void attn_kernel(
    const unsigned short* __restrict__ Qw,
    const unsigned short* __restrict__ Kw,
    const unsigned short* __restrict__ Vtw,
    const float* __restrict__ x,
    float* __restrict__ out)
{
    __shared__ __align__(16) unsigned char smem[32768];
    unsigned short* KsU = (unsigned short*)smem;        // [2 halves][64][64] row-permuted, col-swizzled
    unsigned short* VsU = KsU + 8192;                   // [2 halves][64][64] V^T, col-swizzled
    float* scratch = (float*)smem;                      // epilogue reuse (20480 B)

    const int id  = blockIdx.x;
    const int qt  = id >> 5;                                // 0..15 (128-query tiles)
    const int bh  = ((id & 7) << 2) | ((id >> 3) & 3);      // 4 bh per XCD
    const int tid = threadIdx.x;
    const int w   = tid >> 6, lane = tid & 63;
    const int l16 = lane & 15, quad = lane >> 4;
    const int g   = w & 3;      // q-group: queries g*32 .. g*32+31
    const int p   = w >> 2;     // key-half (1024 keys)
    const int xq  = l16 & 7;    // read-side swizzle key

    const unsigned short* Qb = Qw + ((size_t)bh * SEQ + qt * 128 + g * 32 + l16) * DHEAD;
    bf16x8 qf[2][2];
    #pragma unroll
    for (int qh = 0; qh < 2; qh++) {
        qf[qh][0] = *(const bf16x8*)(Qb + qh * 16 * DHEAD + quad * 8);
        qf[qh][1] = *(const bf16x8*)(Qb + qh * 16 * DHEAD + 32 + quad * 8);
    }

    bf16x8 ones;
    #pragma unroll
    for (int j = 0; j < 8; j++) ones[j] = (bf16)1.0f;

    f32x4 o[2][4], dsum[2];
    const f32x4 fzero = {0.f, 0.f, 0.f, 0.f};
    #pragma unroll
    for (int qh = 0; qh < 2; qh++) {
        #pragma unroll
        for (int d = 0; d < 4; d++) o[qh][d] = fzero;
        dsum[qh] = fzero;
    }

    const unsigned short* Kg = Kw  + (size_t)bh * SEQ * DHEAD;
    const unsigned short* Vg = Vtw + (size_t)bh * DHEAD * SEQ;

    // --- staging source address setup (per-lane) ---
    // Each wave DMAs physical LDS rows 8w..8w+7 of each of the 4 tiles.
    // gl_lds dest = uniform base + lane*16B  => lane l -> phys row 8w+(l>>3), slot l&7.
    // Phys slot (pr, c16) must hold:  K[rlog(pr)][c16 ^ (pr&7)]  /  V^T[pr][c16 ^ (pr&7)]
    // rlog derived from the MFMA fragment layouts (S^T C-regs == PV A-frags):
    //   rlog(p) = ((p>>2)&3)*8 + ((p>>4)&1)*4 + (p&3) + (p&32)
    const int sl   = lane >> 3;                 // 0..7 (== pr & 7 since rows start at 8w)
    const int c16s = (lane & 7) ^ sl;           // pre-swizzled 16B slot in source
    const int pr   = 8 * w + sl;                // physical row this lane stages
    const int rlog = ((pr >> 2) & 3) * 8 + ((pr >> 4) & 1) * 4 + (pr & 3) + (pr & 32);
    const size_t koff = (size_t)rlog * DHEAD + c16s * 8;   // ushorts, tile-relative
    const size_t voff = (size_t)pr * SEQ + c16s * 8;       // ushorts, tile-relative

    for (int t = 0; t < KT; t++) {
        __syncthreads();   // readers of tile t-1 done
        const size_t kb = (size_t)(t * 64) * DHEAD;
        __builtin_amdgcn_global_load_lds((gu32*)(Kg + kb + koff),
                                         (su32*)&KsU[w * 512], 16, 0, 0);
        __builtin_amdgcn_global_load_lds((gu32*)(Kg + kb + (size_t)1024 * DHEAD + koff),
                                         (su32*)&KsU[4096 + w * 512], 16, 0, 0);
        __builtin_amdgcn_global_load_lds((gu32*)(Vg + voff + t * 64),
                                         (su32*)&VsU[w * 512], 16, 0, 0);
        __builtin_amdgcn_global_load_lds((gu32*)(Vg + voff + 1024 + t * 64),
                                         (su32*)&VsU[4096 + w * 512], 16, 0, 0);
        __syncthreads();   // compiler drains vmcnt(0) before s_barrier -> staging visible

        const unsigned short* Kb = KsU + p * 4096;
        const unsigned short* Vb = VsU + p * 4096;

        // S^T = K_perm · Q^T for both query-sixteens; each kf read feeds 2 MFMAs
        f32x4 sacc[2][4];   // [qh][ki]
        #pragma unroll
        for (int qh = 0; qh < 2; qh++)
            #pragma unroll
            for (int ki = 0; ki < 4; ki++) sacc[qh][ki] = fzero;
        #pragma unroll
        for (int s = 0; s < 2; s++) {
            const int col = ((s * 4 + quad) ^ xq) * 8;   // swizzled 16B slot
            #pragma unroll
            for (int ki = 0; ki < 4; ki++) {
                bf16x8 kf = *(const bf16x8*)(&Kb[(ki * 16 + l16) * 64 + col]);
                sacc[0][ki] = __builtin_amdgcn_mfma_f32_16x16x32_bf16(kf, qf[0][s], sacc[0][ki], 0, 0, 0);
                sacc[1][ki] = __builtin_amdgcn_mfma_f32_16x16x32_bf16(kf, qf[1][s], sacc[1][ki], 0, 0, 0);
            }
        }

        // p = exp2(s); C-regs are the PV A-frags; denominator via ones-MFMA
        bf16x8 pf[2][2];
        #pragma unroll
        for (int qh = 0; qh < 2; qh++)
            #pragma unroll
            for (int s = 0; s < 2; s++)
                #pragma unroll
                for (int half = 0; half < 2; half++) {
                    int ki = 2 * s + half;
                    #pragma unroll
                    for (int r = 0; r < 4; r++)
                        pf[qh][s][half * 4 + r] = (bf16)__builtin_amdgcn_exp2f(sacc[qh][ki][r]);
                }

        #pragma unroll
        for (int s = 0; s < 2; s++) {
            const int col = ((s * 4 + quad) ^ xq) * 8;
            dsum[0] = __builtin_amdgcn_mfma_f32_16x16x32_bf16(pf[0][s], ones, dsum[0], 0, 0, 0);
            dsum[1] = __builtin_amdgcn_mfma_f32_16x16x32_bf16(pf[1][s], ones, dsum[1], 0, 0, 0);
            #pragma unroll
            for (int d = 0; d < 4; d++) {
                bf16x8 vf = *(const bf16x8*)(&Vb[(d * 16 + l16) * 64 + col]);
                o[0][d] = __builtin_amdgcn_mfma_f32_16x16x32_bf16(pf[0][s], vf, o[0][d], 0, 0, 0);
                o[1][d] = __builtin_amdgcn_mfma_f32_16x16x32_bf16(pf[1][s], vf, o[1][d], 0, 0, 0);
            }
        }
    }

    // ---- combine the two key-half partials: 2 passes through 20480B scratch ----
    __syncthreads();   // all waves done reading K/V LDS
    #pragma unroll
    for (int ch = 0; ch < 2; ch++) {
        if (ch) __syncthreads();             // pass-0 readers done before overwrite
        if (p == 1) {
            float* sc = scratch + ((size_t)(g * 64 + lane)) * 20;
            #pragma unroll
            for (int di = 0; di < 4; di++)
                *(f32x4*)(sc + di * 4) = o[ch][di];
            *(f32x4*)(sc + 16) = dsum[ch];
        }
        __syncthreads();
        if (p == 0) {
            float* sc = scratch + ((size_t)(g * 64 + lane)) * 20;
            #pragma unroll
            for (int di = 0; di < 4; di++)
                o[ch][di] += *(const f32x4*)(sc + di * 4);
            dsum[ch] += *(const f32x4*)(sc + 16);
        }
    }

    if (p == 0) {
        const int b = bh >> 4, h = bh & 15;
        #pragma unroll
        for (int ch = 0; ch < 2; ch++) {
            float lr[4];
            #pragma unroll
            for (int r = 0; r < 4; r++) lr[r] = __builtin_amdgcn_rcpf(dsum[ch][r]);
            #pragma unroll
            for (int di = 0; di < 4; di++)
                #pragma unroll
                for (int r = 0; r < 4; r++) {
                    int np  = qt * 128 + g * 32 + ch * 16 + quad * 4 + r;
                    int col = h * 64 + di * 16 + l16;
                    size_t gidx = ((size_t)(b * SEQ + np)) * DIM + col;
                    out[gidx] = o[ch][di][r] * lr[r] + x[gidx];
                }
        }
    }
}

extern "C" void kernel_launch(void* const* d_in, const int* in_sizes, int n_in,
                              void* d_out, int out_size, void* d_ws, size_t ws_size,
                              hipStream_t stream) {
    const float* x  = (const float*)d_in[0];   // [2,2048,1024]
    const float* Wq = (const float*)d_in[1];   // [1024,3072]
    float* out = (float*)d_out;

    unsigned short* xb = (unsigned short*)d_ws;                  // [4096][1024]
    unsigned short* Wt = xb + (size_t)M_TOT * DIM;               // [3072][1024]
    unsigned short* Qw = Wt + (size_t)NQKV * DIM;                // [32][2048][64]
    unsigned short* Kw = Qw + (size_t)32 * SEQ * DHEAD;          // [32][2048][64]
    unsigned short* Vt = Kw + (size_t)32 * SEQ * DHEAD;          // [32][64][2048]

    prep_kernel<<<CAST_BLOCKS + TR_NB * (DIM / 64), 256, 0, stream>>>(x, xb, Wq, Wt);
    qkv_gemm_kernel<<<dim3(NQKV / 128, M_TOT / 128), 256, 0, stream>>>(xb, Wt, Qw, Kw, Vt);
    attn_kernel<<<(SEQ / 128) * 32, 512, 0, stream>>>(Qw, Kw, Vt, x, out);
}

// Round 8
// 148.974 us; speedup vs baseline: 1.4997x; 1.0743x over previous
//
#include <hip/hip_runtime.h>

#define DIM   1024
#define NQKV  3072
#define SEQ   2048
#define HEADS 16
#define DHEAD 64
#define M_TOT 4096   // batch(2) * seq(2048)

typedef __bf16 bf16;
typedef __bf16 bf16x8 __attribute__((ext_vector_type(8)));
typedef float  f32x4  __attribute__((ext_vector_type(4)));

typedef const __attribute__((address_space(1))) unsigned int gu32;
typedef __attribute__((address_space(3))) unsigned int su32;

static __device__ __forceinline__ unsigned short f2b(float f) {
    bf16 h = (bf16)f;
    return __builtin_bit_cast(unsigned short, h);
}

// ---------------- kernel 1: fused prep (cast x -> bf16 | transpose+scale W) ----------------
// R8: transpose in 64x64 tiles, float4 global reads, uint4 global writes.
#define CAST_BLOCKS (M_TOT * DIM / (256 * 4))
#define TR_NB (NQKV / 64)   // 48
__global__ void prep_kernel(const float* __restrict__ x,
                            unsigned short* __restrict__ xb,
                            const float* __restrict__ W,
                            unsigned short* __restrict__ Wt) {
    __shared__ float tile[64][65];   // [n_local][k_local], padded
    const int id  = blockIdx.x;
    const int tid = threadIdx.x;
    if (id < CAST_BLOCKS) {
        int i = (id * 256 + tid) * 4;
        float4 v = *(const float4*)(x + i);
        ushort4 o;
        o.x = f2b(v.x); o.y = f2b(v.y); o.z = f2b(v.z); o.w = f2b(v.w);
        *(ushort4*)(xb + i) = o;
    } else {
        int t  = id - CAST_BLOCKS;
        int nb = t % TR_NB;
        int kb = t / TR_NB;          // 0..15
        #pragma unroll
        for (int p = 0; p < 4; p++) {
            int kl = p * 16 + (tid >> 4);        // 0..63
            int nl = (tid & 15) * 4;             // 0..60
            float4 v = *(const float4*)&W[(size_t)(kb * 64 + kl) * NQKV + nb * 64 + nl];
            tile[nl + 0][kl] = v.x;
            tile[nl + 1][kl] = v.y;
            tile[nl + 2][kl] = v.z;
            tile[nl + 3][kl] = v.w;
        }
        __syncthreads();
        #pragma unroll
        for (int p = 0; p < 2; p++) {
            int nl = p * 32 + (tid >> 3);        // 0..63
            int k8 = (tid & 7) * 8;              // 0..56
            int n  = nb * 64 + nl;
            float s = (n < 1024) ? 0.18033688f : 1.0f;   // 0.125 * log2(e)
            float4 a = *(const float4*)&tile[nl][k8];
            float4 b = *(const float4*)&tile[nl][k8 + 4];
            ushort4 o0, o1;
            o0.x = f2b(a.x * s); o0.y = f2b(a.y * s); o0.z = f2b(a.z * s); o0.w = f2b(a.w * s);
            o1.x = f2b(b.x * s); o1.y = f2b(b.y * s); o1.z = f2b(b.z * s); o1.w = f2b(b.w * s);
            uint4 pk;
            pk.x = ((unsigned)o0.y << 16) | o0.x;
            pk.y = ((unsigned)o0.w << 16) | o0.z;
            pk.z = ((unsigned)o1.y << 16) | o1.x;
            pk.w = ((unsigned)o1.w << 16) | o1.z;
            *(uint4*)&Wt[(size_t)n * DIM + kb * 64 + k8] = pk;
        }
    }
}

// ---------------- kernel 2: QKV GEMM, LDS-restaged coalesced epilogue ----------------
// R14: SQ_LDS_BANK_CONFLICT 9.6M = 12.2 extra cyc per ds_read_b128 (~26 of the
// 55 us on the LDS pipe). Cause: [128][64] tile column-slice reads -- 16 lanes,
// same 16B slot, different rows -> 16-way bank serialization. Fix (proven in
// attn R13): XOR-swizzle slot with row&7 on BOTH sides -- pre-swizzled per-lane
// GLOBAL SOURCE for global_load_lds (dest linear) + matching XOR on reads.
// Read slot = (s*4+quad)^(l16&7): 8 lanes/slot-group = b128 minimum aliasing.
// Source stays coalesced (slots permuted within each 128B row). Bit-identical.
#define LDC 136
__global__ __launch_bounds__(256) void qkv_gemm_kernel(
    const unsigned short* __restrict__ A,
    const unsigned short* __restrict__ Bt,
    unsigned short* __restrict__ Qw,
    unsigned short* __restrict__ Kw,
    unsigned short* __restrict__ Vtw)
{
    __shared__ __align__(16) unsigned char smem[128 * LDC * 2];   // 34816 B
    unsigned short* As = (unsigned short*)smem;
    unsigned short* Bs = (unsigned short*)(smem + 16384);
    unsigned short* Cs = (unsigned short*)smem;

    const int tid  = threadIdx.x;
    const int m0   = blockIdx.y * 128;
    const int n0   = blockIdx.x * 128;
    const int w    = tid >> 6;
    const int lane = tid & 63;
    const int l16  = lane & 15;
    const int quad = lane >> 4;
    const int wm   = (w >> 1) * 64;
    const int wn   = (w & 1) * 64;
    const int srow = lane >> 3;                      // 0..7 == staged row & 7
    const int scol = ((lane & 7) ^ srow) * 8;        // pre-swizzled source slot
    const int xa   = l16 & 7;                        // read-side swizzle key

    f32x4 acc[4][4];
    const f32x4 fzero = {0.f, 0.f, 0.f, 0.f};
    for (int i = 0; i < 4; i++)
        for (int j = 0; j < 4; j++) acc[i][j] = fzero;

    const unsigned short* Ag = A  + (size_t)(m0 + w * 32 + srow) * DIM + scol;
    const unsigned short* Bg = Bt + (size_t)(n0 + w * 32 + srow) * DIM + scol;

    for (int kt = 0; kt < DIM; kt += 64) {
        #pragma unroll
        for (int j = 0; j < 4; j++) {
            __builtin_amdgcn_global_load_lds((gu32*)(Ag + kt + (size_t)j * 8 * DIM),
                                             (su32*)&As[(w * 32 + j * 8) * 64], 16, 0, 0);
            __builtin_amdgcn_global_load_lds((gu32*)(Bg + kt + (size_t)j * 8 * DIM),
                                             (su32*)&Bs[(w * 32 + j * 8) * 64], 16, 0, 0);
        }
        __syncthreads();
        #pragma unroll
        for (int s = 0; s < 2; s++) {
            const int col = ((s * 4 + quad) ^ xa) * 8;   // swizzled 16B slot
            bf16x8 af[4], bfr[4];
            #pragma unroll
            for (int i = 0; i < 4; i++) {
                af[i]  = *(const bf16x8*)(&As[(wm + i * 16 + l16) * 64 + col]);
                bfr[i] = *(const bf16x8*)(&Bs[(wn + i * 16 + l16) * 64 + col]);
            }
            #pragma unroll
            for (int i = 0; i < 4; i++)
                #pragma unroll
                for (int j = 0; j < 4; j++)
                    acc[i][j] = __builtin_amdgcn_mfma_f32_16x16x32_bf16(af[i], bfr[j], acc[i][j], 0, 0, 0);
        }
        __syncthreads();
    }

    const int part = n0 >> 10;
    const int h0   = (n0 & 1023) >> 6;
    const int b    = m0 >> 11;
    const int np0  = m0 & 2047;

    if (part < 2) {
        #pragma unroll
        for (int i = 0; i < 4; i++)
            #pragma unroll
            for (int j = 0; j < 4; j++)
                #pragma unroll
                for (int r = 0; r < 4; r++)
                    Cs[(wm + i * 16 + quad * 4 + r) * LDC + wn + j * 16 + l16] = f2b(acc[i][j][r]);
        __syncthreads();
        unsigned short* dst = (part == 0) ? Qw : Kw;
        #pragma unroll
        for (int pass = 0; pass < 8; pass++) {
            int mi = pass * 16 + (tid >> 4);
            int ci = (tid & 15) * 8;
            uint4 v = *(const uint4*)&Cs[mi * LDC + ci];
            int bh = b * HEADS + h0 + (ci >> 6);
            *(uint4*)&dst[((size_t)bh * SEQ + np0 + mi) * DHEAD + (ci & 63)] = v;
        }
    } else {
        #pragma unroll
        for (int i = 0; i < 4; i++)
            #pragma unroll
            for (int j = 0; j < 4; j++) {
                ushort4 pk;
                pk.x = f2b(acc[i][j][0]); pk.y = f2b(acc[i][j][1]);
                pk.z = f2b(acc[i][j][2]); pk.w = f2b(acc[i][j][3]);
                *(ushort4*)&Cs[(wn + j * 16 + l16) * LDC + wm + i * 16 + quad * 4] = pk;
            }
        __syncthreads();
        #pragma unroll
        for (int pass = 0; pass < 8; pass++) {
            int ci = pass * 16 + (tid >> 4);
            int mi = (tid & 15) * 8;
            uint4 v = *(const uint4*)&Cs[ci * LDC + mi];
            int bh = b * HEADS + h0 + (ci >> 6);
            *(uint4*)&Vtw[((size_t)bh * DHEAD + (ci & 63)) * SEQ + np0 + mi] = v;
        }
    }
}

// ---------------- kernel 3: flash attention + residual ----------------
// R13 (kept): 512-thread blocks (8 waves = 4 q-groups x 2 key-halves), grid
// 512 -> 2 blocks/CU = 16 waves/CU. K/V staged via global_load_lds with
// pre-swizzled+row-permuted per-lane source (linear dest); XOR col swizzle
// makes column-sliced b128 reads even. VGPR<=128 (R6 lesson), 16B rows,
// single-buffered 32768B LDS. Dropped attn below the gemm in the profile.
#define KT 16                   // key tiles per key-half
__global__ __launch_bounds__(512, 4) void attn_kernel(
    const unsigned short* __restrict__ Qw,
    const unsigned short* __restrict__ Kw,
    const unsigned short* __restrict__ Vtw,
    const float* __restrict__ x,
    float* __restrict__ out)
{
    __shared__ __align__(16) unsigned char smem[32768];
    unsigned short* KsU = (unsigned short*)smem;        // [2 halves][64][64] row-permuted, col-swizzled
    unsigned short* VsU = KsU + 8192;                   // [2 halves][64][64] V^T, col-swizzled
    float* scratch = (float*)smem;                      // epilogue reuse (20480 B)

    const int id  = blockIdx.x;
    const int qt  = id >> 5;                                // 0..15 (128-query tiles)
    const int bh  = ((id & 7) << 2) | ((id >> 3) & 3);      // 4 bh per XCD
    const int tid = threadIdx.x;
    const int w   = tid >> 6, lane = tid & 63;
    const int l16 = lane & 15, quad = lane >> 4;
    const int g   = w & 3;      // q-group: queries g*32 .. g*32+31
    const int p   = w >> 2;     // key-half (1024 keys)
    const int xq  = l16 & 7;    // read-side swizzle key

    const unsigned short* Qb = Qw + ((size_t)bh * SEQ + qt * 128 + g * 32 + l16) * DHEAD;
    bf16x8 qf[2][2];
    #pragma unroll
    for (int qh = 0; qh < 2; qh++) {
        qf[qh][0] = *(const bf16x8*)(Qb + qh * 16 * DHEAD + quad * 8);
        qf[qh][1] = *(const bf16x8*)(Qb + qh * 16 * DHEAD + 32 + quad * 8);
    }

    bf16x8 ones;
    #pragma unroll
    for (int j = 0; j < 8; j++) ones[j] = (bf16)1.0f;

    f32x4 o[2][4], dsum[2];
    const f32x4 fzero = {0.f, 0.f, 0.f, 0.f};
    #pragma unroll
    for (int qh = 0; qh < 2; qh++) {
        #pragma unroll
        for (int d = 0; d < 4; d++) o[qh][d] = fzero;
        dsum[qh] = fzero;
    }

    const unsigned short* Kg = Kw  + (size_t)bh * SEQ * DHEAD;
    const unsigned short* Vg = Vtw + (size_t)bh * DHEAD * SEQ;

    // --- staging source address setup (per-lane) ---
    const int sl   = lane >> 3;                 // 0..7 (== pr & 7 since rows start at 8w)
    const int c16s = (lane & 7) ^ sl;           // pre-swizzled 16B slot in source
    const int pr   = 8 * w + sl;                // physical row this lane stages
    const int rlog = ((pr >> 2) & 3) * 8 + ((pr >> 4) & 1) * 4 + (pr & 3) + (pr & 32);
    const size_t koff = (size_t)rlog * DHEAD + c16s * 8;   // ushorts, tile-relative
    const size_t voff = (size_t)pr * SEQ + c16s * 8;       // ushorts, tile-relative

    for (int t = 0; t < KT; t++) {
        __syncthreads();   // readers of tile t-1 done
        const size_t kb = (size_t)(t * 64) * DHEAD;
        __builtin_amdgcn_global_load_lds((gu32*)(Kg + kb + koff),
                                         (su32*)&KsU[w * 512], 16, 0, 0);
        __builtin_amdgcn_global_load_lds((gu32*)(Kg + kb + (size_t)1024 * DHEAD + koff),
                                         (su32*)&KsU[4096 + w * 512], 16, 0, 0);
        __builtin_amdgcn_global_load_lds((gu32*)(Vg + voff + t * 64),
                                         (su32*)&VsU[w * 512], 16, 0, 0);
        __builtin_amdgcn_global_load_lds((gu32*)(Vg + voff + 1024 + t * 64),
                                         (su32*)&VsU[4096 + w * 512], 16, 0, 0);
        __syncthreads();   // staging visible

        const unsigned short* Kb = KsU + p * 4096;
        const unsigned short* Vb = VsU + p * 4096;

        // S^T = K_perm · Q^T for both query-sixteens; each kf read feeds 2 MFMAs
        f32x4 sacc[2][4];   // [qh][ki]
        #pragma unroll
        for (int qh = 0; qh < 2; qh++)
            #pragma unroll
            for (int ki = 0; ki < 4; ki++) sacc[qh][ki] = fzero;
        #pragma unroll
        for (int s = 0; s < 2; s++) {
            const int col = ((s * 4 + quad) ^ xq) * 8;   // swizzled 16B slot
            #pragma unroll
            for (int ki = 0; ki < 4; ki++) {
                bf16x8 kf = *(const bf16x8*)(&Kb[(ki * 16 + l16) * 64 + col]);
                sacc[0][ki] = __builtin_amdgcn_mfma_f32_16x16x32_bf16(kf, qf[0][s], sacc[0][ki], 0, 0, 0);
                sacc[1][ki] = __builtin_amdgcn_mfma_f32_16x16x32_bf16(kf, qf[1][s], sacc[1][ki], 0, 0, 0);
            }
        }

        // p = exp2(s); C-regs are the PV A-frags; denominator via ones-MFMA
        bf16x8 pf[2][2];
        #pragma unroll
        for (int qh = 0; qh < 2; qh++)
            #pragma unroll
            for (int s = 0; s < 2; s++)
                #pragma unroll
                for (int half = 0; half < 2; half++) {
                    int ki = 2 * s + half;
                    #pragma unroll
                    for (int r = 0; r < 4; r++)
                        pf[qh][s][half * 4 + r] = (bf16)__builtin_amdgcn_exp2f(sacc[qh][ki][r]);
                }

        #pragma unroll
        for (int s = 0; s < 2; s++) {
            const int col = ((s * 4 + quad) ^ xq) * 8;
            dsum[0] = __builtin_amdgcn_mfma_f32_16x16x32_bf16(pf[0][s], ones, dsum[0], 0, 0, 0);
            dsum[1] = __builtin_amdgcn_mfma_f32_16x16x32_bf16(pf[1][s], ones, dsum[1], 0, 0, 0);
            #pragma unroll
            for (int d = 0; d < 4; d++) {
                bf16x8 vf = *(const bf16x8*)(&Vb[(d * 16 + l16) * 64 + col]);
                o[0][d] = __builtin_amdgcn_mfma_f32_16x16x32_bf16(pf[0][s], vf, o[0][d], 0, 0, 0);
                o[1][d] = __builtin_amdgcn_mfma_f32_16x16x32_bf16(pf[1][s], vf, o[1][d], 0, 0, 0);
            }
        }
    }

    // ---- combine the two key-half partials: 2 passes through 20480B scratch ----
    __syncthreads();   // all waves done reading K/V LDS
    #pragma unroll
    for (int ch = 0; ch < 2; ch++) {
        if (ch) __syncthreads();             // pass-0 readers done before overwrite
        if (p == 1) {
            float* sc = scratch + ((size_t)(g * 64 + lane)) * 20;
            #pragma unroll
            for (int di = 0; di < 4; di++)
                *(f32x4*)(sc + di * 4) = o[ch][di];
            *(f32x4*)(sc + 16) = dsum[ch];
        }
        __syncthreads();
        if (p == 0) {
            float* sc = scratch + ((size_t)(g * 64 + lane)) * 20;
            #pragma unroll
            for (int di = 0; di < 4; di++)
                o[ch][di] += *(const f32x4*)(sc + di * 4);
            dsum[ch] += *(const f32x4*)(sc + 16);
        }
    }

    if (p == 0) {
        const int b = bh >> 4, h = bh & 15;
        #pragma unroll
        for (int ch = 0; ch < 2; ch++) {
            float lr[4];
            #pragma unroll
            for (int r = 0; r < 4; r++) lr[r] = __builtin_amdgcn_rcpf(dsum[ch][r]);
            #pragma unroll
            for (int di = 0; di < 4; di++)
                #pragma unroll
                for (int r = 0; r < 4; r++) {
                    int np  = qt * 128 + g * 32 + ch * 16 + quad * 4 + r;
                    int col = h * 64 + di * 16 + l16;
                    size_t gidx = ((size_t)(b * SEQ + np)) * DIM + col;
                    out[gidx] = o[ch][di][r] * lr[r] + x[gidx];
                }
        }
    }
}

extern "C" void kernel_launch(void* const* d_in, const int* in_sizes, int n_in,
                              void* d_out, int out_size, void* d_ws, size_t ws_size,
                              hipStream_t stream) {
    const float* x  = (const float*)d_in[0];   // [2,2048,1024]
    const float* Wq = (const float*)d_in[1];   // [1024,3072]
    float* out = (float*)d_out;

    unsigned short* xb = (unsigned short*)d_ws;                  // [4096][1024]
    unsigned short* Wt = xb + (size_t)M_TOT * DIM;               // [3072][1024]
    unsigned short* Qw = Wt + (size_t)NQKV * DIM;                // [32][2048][64]
    unsigned short* Kw = Qw + (size_t)32 * SEQ * DHEAD;          // [32][2048][64]
    unsigned short* Vt = Kw + (size_t)32 * SEQ * DHEAD;          // [32][64][2048]

    prep_kernel<<<CAST_BLOCKS + TR_NB * (DIM / 64), 256, 0, stream>>>(x, xb, Wq, Wt);
    qkv_gemm_kernel<<<dim3(NQKV / 128, M_TOT / 128), 256, 0, stream>>>(xb, Wt, Qw, Kw, Vt);
    attn_kernel<<<(SEQ / 128) * 32, 512, 0, stream>>>(Qw, Kw, Vt, x, out);
}

// Round 9
// 147.330 us; speedup vs baseline: 1.5164x; 1.0112x over previous
//
#include <hip/hip_runtime.h>

#define DIM   1024
#define NQKV  3072
#define SEQ   2048
#define HEADS 16
#define DHEAD 64
#define M_TOT 4096   // batch(2) * seq(2048)

typedef __bf16 bf16;
typedef __bf16 bf16x8 __attribute__((ext_vector_type(8)));
typedef float  f32x4  __attribute__((ext_vector_type(4)));

typedef const __attribute__((address_space(1))) unsigned int gu32;
typedef __attribute__((address_space(3))) unsigned int su32;

static __device__ __forceinline__ unsigned short f2b(float f) {
    bf16 h = (bf16)f;
    return __builtin_bit_cast(unsigned short, h);
}

// ---------------- kernel 1: fused prep (cast x -> bf16 | transpose+scale W) ----------------
// R8: transpose in 64x64 tiles, float4 global reads, uint4 global writes.
#define CAST_BLOCKS (M_TOT * DIM / (256 * 4))
#define TR_NB (NQKV / 64)   // 48
__global__ void prep_kernel(const float* __restrict__ x,
                            unsigned short* __restrict__ xb,
                            const float* __restrict__ W,
                            unsigned short* __restrict__ Wt) {
    __shared__ float tile[64][65];   // [n_local][k_local], padded
    const int id  = blockIdx.x;
    const int tid = threadIdx.x;
    if (id < CAST_BLOCKS) {
        int i = (id * 256 + tid) * 4;
        float4 v = *(const float4*)(x + i);
        ushort4 o;
        o.x = f2b(v.x); o.y = f2b(v.y); o.z = f2b(v.z); o.w = f2b(v.w);
        *(ushort4*)(xb + i) = o;
    } else {
        int t  = id - CAST_BLOCKS;
        int nb = t % TR_NB;
        int kb = t / TR_NB;          // 0..15
        #pragma unroll
        for (int p = 0; p < 4; p++) {
            int kl = p * 16 + (tid >> 4);        // 0..63
            int nl = (tid & 15) * 4;             // 0..60
            float4 v = *(const float4*)&W[(size_t)(kb * 64 + kl) * NQKV + nb * 64 + nl];
            tile[nl + 0][kl] = v.x;
            tile[nl + 1][kl] = v.y;
            tile[nl + 2][kl] = v.z;
            tile[nl + 3][kl] = v.w;
        }
        __syncthreads();
        #pragma unroll
        for (int p = 0; p < 2; p++) {
            int nl = p * 32 + (tid >> 3);        // 0..63
            int k8 = (tid & 7) * 8;              // 0..56
            int n  = nb * 64 + nl;
            float s = (n < 1024) ? 0.18033688f : 1.0f;   // 0.125 * log2(e)
            float4 a = *(const float4*)&tile[nl][k8];
            float4 b = *(const float4*)&tile[nl][k8 + 4];
            ushort4 o0, o1;
            o0.x = f2b(a.x * s); o0.y = f2b(a.y * s); o0.z = f2b(a.z * s); o0.w = f2b(a.w * s);
            o1.x = f2b(b.x * s); o1.y = f2b(b.y * s); o1.z = f2b(b.z * s); o1.w = f2b(b.w * s);
            uint4 pk;
            pk.x = ((unsigned)o0.y << 16) | o0.x;
            pk.y = ((unsigned)o0.w << 16) | o0.z;
            pk.z = ((unsigned)o1.y << 16) | o1.x;
            pk.w = ((unsigned)o1.w << 16) | o1.z;
            *(uint4*)&Wt[(size_t)n * DIM + kb * 64 + k8] = pk;
        }
    }
}

// ---------------- kernel 2: QKV GEMM ----------------
// R14 (kept): XOR-swizzled LDS (pre-swizzled gl_lds source + swizzled reads),
// conflicts 9.6M -> ~0, 55.2 -> ~42 us.
// R15: the remaining stall was the serial load-drain -- stage -> barrier
// (vmcnt(0) drain) -> compute paid full global latency every K-step. Now
// 2-phase double-buffer (T3-minimal): stage t+1 into buf^1, compute t, ONE
// barrier/iter whose drain lands after the compute phase. LDS 64KB (As/Bs x2,
// Cs epilogue reuses buf0); blocks/CU 3 -> 2 (LDS-bound) -- pipelining vs
// residency trade, watch counters.
#define LDC 136
__global__ __launch_bounds__(256) void qkv_gemm_kernel(
    const unsigned short* __restrict__ A,
    const unsigned short* __restrict__ Bt,
    unsigned short* __restrict__ Qw,
    unsigned short* __restrict__ Kw,
    unsigned short* __restrict__ Vtw)
{
    __shared__ __align__(16) unsigned char smem[65536];   // 2 bufs x (As 16K | Bs 16K)
    unsigned short* Cs = (unsigned short*)smem;           // epilogue reuse (34816 B)

    const int tid  = threadIdx.x;
    const int m0   = blockIdx.y * 128;
    const int n0   = blockIdx.x * 128;
    const int w    = tid >> 6;
    const int lane = tid & 63;
    const int l16  = lane & 15;
    const int quad = lane >> 4;
    const int wm   = (w >> 1) * 64;
    const int wn   = (w & 1) * 64;
    const int srow = lane >> 3;                      // 0..7 == staged row & 7
    const int scol = ((lane & 7) ^ srow) * 8;        // pre-swizzled source slot
    const int xa   = l16 & 7;                        // read-side swizzle key

    f32x4 acc[4][4];
    const f32x4 fzero = {0.f, 0.f, 0.f, 0.f};
    for (int i = 0; i < 4; i++)
        for (int j = 0; j < 4; j++) acc[i][j] = fzero;

    const unsigned short* Ag = A  + (size_t)(m0 + w * 32 + srow) * DIM + scol;
    const unsigned short* Bg = Bt + (size_t)(n0 + w * 32 + srow) * DIM + scol;

    // prologue: stage K-step 0 into buf 0
    {
        unsigned short* As0 = (unsigned short*)smem;
        unsigned short* Bs0 = (unsigned short*)(smem + 16384);
        #pragma unroll
        for (int j = 0; j < 4; j++) {
            __builtin_amdgcn_global_load_lds((gu32*)(Ag + (size_t)j * 8 * DIM),
                                             (su32*)&As0[(w * 32 + j * 8) * 64], 16, 0, 0);
            __builtin_amdgcn_global_load_lds((gu32*)(Bg + (size_t)j * 8 * DIM),
                                             (su32*)&Bs0[(w * 32 + j * 8) * 64], 16, 0, 0);
        }
    }
    __syncthreads();

    for (int ki = 0; ki < 16; ki++) {
        const int cur = ki & 1, nxt = cur ^ 1;
        if (ki < 15) {   // stage K-step ki+1 into the other buffer (flies under compute)
            const int kt = (ki + 1) * 64;
            unsigned short* Asn = (unsigned short*)(smem + nxt * 32768);
            unsigned short* Bsn = (unsigned short*)(smem + nxt * 32768 + 16384);
            #pragma unroll
            for (int j = 0; j < 4; j++) {
                __builtin_amdgcn_global_load_lds((gu32*)(Ag + kt + (size_t)j * 8 * DIM),
                                                 (su32*)&Asn[(w * 32 + j * 8) * 64], 16, 0, 0);
                __builtin_amdgcn_global_load_lds((gu32*)(Bg + kt + (size_t)j * 8 * DIM),
                                                 (su32*)&Bsn[(w * 32 + j * 8) * 64], 16, 0, 0);
            }
        }
        const unsigned short* As = (const unsigned short*)(smem + cur * 32768);
        const unsigned short* Bs = (const unsigned short*)(smem + cur * 32768 + 16384);
        #pragma unroll
        for (int s = 0; s < 2; s++) {
            const int col = ((s * 4 + quad) ^ xa) * 8;   // swizzled 16B slot
            bf16x8 af[4], bfr[4];
            #pragma unroll
            for (int i = 0; i < 4; i++) {
                af[i]  = *(const bf16x8*)(&As[(wm + i * 16 + l16) * 64 + col]);
                bfr[i] = *(const bf16x8*)(&Bs[(wn + i * 16 + l16) * 64 + col]);
            }
            #pragma unroll
            for (int i = 0; i < 4; i++)
                #pragma unroll
                for (int j = 0; j < 4; j++)
                    acc[i][j] = __builtin_amdgcn_mfma_f32_16x16x32_bf16(af[i], bfr[j], acc[i][j], 0, 0, 0);
        }
        __syncthreads();   // drains vmcnt: ki+1 resident; readers of cur done
    }

    const int part = n0 >> 10;
    const int h0   = (n0 & 1023) >> 6;
    const int b    = m0 >> 11;
    const int np0  = m0 & 2047;

    if (part < 2) {
        #pragma unroll
        for (int i = 0; i < 4; i++)
            #pragma unroll
            for (int j = 0; j < 4; j++)
                #pragma unroll
                for (int r = 0; r < 4; r++)
                    Cs[(wm + i * 16 + quad * 4 + r) * LDC + wn + j * 16 + l16] = f2b(acc[i][j][r]);
        __syncthreads();
        unsigned short* dst = (part == 0) ? Qw : Kw;
        #pragma unroll
        for (int pass = 0; pass < 8; pass++) {
            int mi = pass * 16 + (tid >> 4);
            int ci = (tid & 15) * 8;
            uint4 v = *(const uint4*)&Cs[mi * LDC + ci];
            int bh = b * HEADS + h0 + (ci >> 6);
            *(uint4*)&dst[((size_t)bh * SEQ + np0 + mi) * DHEAD + (ci & 63)] = v;
        }
    } else {
        #pragma unroll
        for (int i = 0; i < 4; i++)
            #pragma unroll
            for (int j = 0; j < 4; j++) {
                ushort4 pk;
                pk.x = f2b(acc[i][j][0]); pk.y = f2b(acc[i][j][1]);
                pk.z = f2b(acc[i][j][2]); pk.w = f2b(acc[i][j][3]);
                *(ushort4*)&Cs[(wn + j * 16 + l16) * LDC + wm + i * 16 + quad * 4] = pk;
            }
        __syncthreads();
        #pragma unroll
        for (int pass = 0; pass < 8; pass++) {
            int ci = pass * 16 + (tid >> 4);
            int mi = (tid & 15) * 8;
            uint4 v = *(const uint4*)&Cs[ci * LDC + mi];
            int bh = b * HEADS + h0 + (ci >> 6);
            *(uint4*)&Vtw[((size_t)bh * DHEAD + (ci & 63)) * SEQ + np0 + mi] = v;
        }
    }
}

// ---------------- kernel 3: flash attention + residual ----------------
// R13 (kept): 512-thread blocks (8 waves = 4 q-groups x 2 key-halves), grid
// 512; gl_lds staging with pre-swizzled+row-permuted source; conflicts = 0.
// R15: kill the per-tile serial load-drain (issue -> barrier-vmcnt0 -> compute
// paid full latency every tile). 2-phase gl_lds double-buffer: stage t+1 into
// buf^1 after the barrier, compute t, one barrier/iter. LDS 32 -> 64 KB;
// VGPR unchanged (~64) so residency should stay 2 blocks/CU (128KB LDS) --
// this is also the clean test of the LDS pool size now VGPR is low.
#define KT 16                   // key tiles per key-half
__global__ __launch_bounds__(512, 4) void attn_kernel(
    const unsigned short* __restrict__ Qw,
    const unsigned short* __restrict__ Kw,
    const unsigned short* __restrict__ Vtw,
    const float* __restrict__ x,
    float* __restrict__ out)
{
    __shared__ __align__(16) unsigned char smem[65536];  // 2 bufs x (K 16K | V 16K)
    unsigned short* base = (unsigned short*)smem;        // buf b: K at b*16384, V at b*16384+8192
    float* scratch = (float*)smem;                       // epilogue reuse (20480 B)

    const int id  = blockIdx.x;
    const int qt  = id >> 5;                                // 0..15 (128-query tiles)
    const int bh  = ((id & 7) << 2) | ((id >> 3) & 3);      // 4 bh per XCD
    const int tid = threadIdx.x;
    const int w   = tid >> 6, lane = tid & 63;
    const int l16 = lane & 15, quad = lane >> 4;
    const int g   = w & 3;      // q-group: queries g*32 .. g*32+31
    const int p   = w >> 2;     // key-half (1024 keys)
    const int xq  = l16 & 7;    // read-side swizzle key

    const unsigned short* Qb = Qw + ((size_t)bh * SEQ + qt * 128 + g * 32 + l16) * DHEAD;
    bf16x8 qf[2][2];
    #pragma unroll
    for (int qh = 0; qh < 2; qh++) {
        qf[qh][0] = *(const bf16x8*)(Qb + qh * 16 * DHEAD + quad * 8);
        qf[qh][1] = *(const bf16x8*)(Qb + qh * 16 * DHEAD + 32 + quad * 8);
    }

    bf16x8 ones;
    #pragma unroll
    for (int j = 0; j < 8; j++) ones[j] = (bf16)1.0f;

    f32x4 o[2][4], dsum[2];
    const f32x4 fzero = {0.f, 0.f, 0.f, 0.f};
    #pragma unroll
    for (int qh = 0; qh < 2; qh++) {
        #pragma unroll
        for (int d = 0; d < 4; d++) o[qh][d] = fzero;
        dsum[qh] = fzero;
    }

    const unsigned short* Kg = Kw  + (size_t)bh * SEQ * DHEAD;
    const unsigned short* Vg = Vtw + (size_t)bh * DHEAD * SEQ;

    // --- staging source address setup (per-lane) ---
    const int sl   = lane >> 3;                 // 0..7 (== pr & 7 since rows start at 8w)
    const int c16s = (lane & 7) ^ sl;           // pre-swizzled 16B slot in source
    const int pr   = 8 * w + sl;                // physical row this lane stages
    const int rlog = ((pr >> 2) & 3) * 8 + ((pr >> 4) & 1) * 4 + (pr & 3) + (pr & 32);
    const size_t koff = (size_t)rlog * DHEAD + c16s * 8;   // ushorts, tile-relative
    const size_t voff = (size_t)pr * SEQ + c16s * 8;       // ushorts, tile-relative

    // prologue: stage tile 0 into buf 0
    {
        unsigned short* Kd = base + w * 512;
        unsigned short* Vd = base + 8192 + w * 512;
        __builtin_amdgcn_global_load_lds((gu32*)(Kg + koff),                         (su32*)Kd, 16, 0, 0);
        __builtin_amdgcn_global_load_lds((gu32*)(Kg + (size_t)1024 * DHEAD + koff), (su32*)(Kd + 4096), 16, 0, 0);
        __builtin_amdgcn_global_load_lds((gu32*)(Vg + voff),                         (su32*)Vd, 16, 0, 0);
        __builtin_amdgcn_global_load_lds((gu32*)(Vg + voff + 1024),                  (su32*)(Vd + 4096), 16, 0, 0);
    }
    __syncthreads();   // tile 0 resident

    for (int t = 0; t < KT; t++) {
        const int cur = t & 1, nxt = cur ^ 1;
        if (t + 1 < KT) {   // stage tile t+1 into the other buffer (flies under compute)
            const size_t kb = (size_t)((t + 1) * 64) * DHEAD;
            const int kv = (t + 1) * 64;
            unsigned short* Kd = base + nxt * 16384 + w * 512;
            unsigned short* Vd = base + nxt * 16384 + 8192 + w * 512;
            __builtin_amdgcn_global_load_lds((gu32*)(Kg + kb + koff),                         (su32*)Kd, 16, 0, 0);
            __builtin_amdgcn_global_load_lds((gu32*)(Kg + kb + (size_t)1024 * DHEAD + koff), (su32*)(Kd + 4096), 16, 0, 0);
            __builtin_amdgcn_global_load_lds((gu32*)(Vg + voff + kv),                        (su32*)Vd, 16, 0, 0);
            __builtin_amdgcn_global_load_lds((gu32*)(Vg + voff + 1024 + kv),                 (su32*)(Vd + 4096), 16, 0, 0);
        }

        const unsigned short* Kb = base + cur * 16384 + p * 4096;
        const unsigned short* Vb = base + cur * 16384 + 8192 + p * 4096;

        // S^T = K_perm · Q^T for both query-sixteens; each kf read feeds 2 MFMAs
        f32x4 sacc[2][4];   // [qh][ki]
        #pragma unroll
        for (int qh = 0; qh < 2; qh++)
            #pragma unroll
            for (int ki = 0; ki < 4; ki++) sacc[qh][ki] = fzero;
        #pragma unroll
        for (int s = 0; s < 2; s++) {
            const int col = ((s * 4 + quad) ^ xq) * 8;   // swizzled 16B slot
            #pragma unroll
            for (int ki = 0; ki < 4; ki++) {
                bf16x8 kf = *(const bf16x8*)(&Kb[(ki * 16 + l16) * 64 + col]);
                sacc[0][ki] = __builtin_amdgcn_mfma_f32_16x16x32_bf16(kf, qf[0][s], sacc[0][ki], 0, 0, 0);
                sacc[1][ki] = __builtin_amdgcn_mfma_f32_16x16x32_bf16(kf, qf[1][s], sacc[1][ki], 0, 0, 0);
            }
        }

        // p = exp2(s); C-regs are the PV A-frags; denominator via ones-MFMA
        bf16x8 pf[2][2];
        #pragma unroll
        for (int qh = 0; qh < 2; qh++)
            #pragma unroll
            for (int s = 0; s < 2; s++)
                #pragma unroll
                for (int half = 0; half < 2; half++) {
                    int ki = 2 * s + half;
                    #pragma unroll
                    for (int r = 0; r < 4; r++)
                        pf[qh][s][half * 4 + r] = (bf16)__builtin_amdgcn_exp2f(sacc[qh][ki][r]);
                }

        #pragma unroll
        for (int s = 0; s < 2; s++) {
            const int col = ((s * 4 + quad) ^ xq) * 8;
            dsum[0] = __builtin_amdgcn_mfma_f32_16x16x32_bf16(pf[0][s], ones, dsum[0], 0, 0, 0);
            dsum[1] = __builtin_amdgcn_mfma_f32_16x16x32_bf16(pf[1][s], ones, dsum[1], 0, 0, 0);
            #pragma unroll
            for (int d = 0; d < 4; d++) {
                bf16x8 vf = *(const bf16x8*)(&Vb[(d * 16 + l16) * 64 + col]);
                o[0][d] = __builtin_amdgcn_mfma_f32_16x16x32_bf16(pf[0][s], vf, o[0][d], 0, 0, 0);
                o[1][d] = __builtin_amdgcn_mfma_f32_16x16x32_bf16(pf[1][s], vf, o[1][d], 0, 0, 0);
            }
        }
        __syncthreads();   // drains vmcnt: tile t+1 resident; readers of cur done
    }

    // ---- combine the two key-half partials: 2 passes through 20480B scratch ----
    #pragma unroll
    for (int ch = 0; ch < 2; ch++) {
        if (ch) __syncthreads();             // pass-0 readers done before overwrite
        if (p == 1) {
            float* sc = scratch + ((size_t)(g * 64 + lane)) * 20;
            #pragma unroll
            for (int di = 0; di < 4; di++)
                *(f32x4*)(sc + di * 4) = o[ch][di];
            *(f32x4*)(sc + 16) = dsum[ch];
        }
        __syncthreads();
        if (p == 0) {
            float* sc = scratch + ((size_t)(g * 64 + lane)) * 20;
            #pragma unroll
            for (int di = 0; di < 4; di++)
                o[ch][di] += *(const f32x4*)(sc + di * 4);
            dsum[ch] += *(const f32x4*)(sc + 16);
        }
    }

    if (p == 0) {
        const int b = bh >> 4, h = bh & 15;
        #pragma unroll
        for (int ch = 0; ch < 2; ch++) {
            float lr[4];
            #pragma unroll
            for (int r = 0; r < 4; r++) lr[r] = __builtin_amdgcn_rcpf(dsum[ch][r]);
            #pragma unroll
            for (int di = 0; di < 4; di++)
                #pragma unroll
                for (int r = 0; r < 4; r++) {
                    int np  = qt * 128 + g * 32 + ch * 16 + quad * 4 + r;
                    int col = h * 64 + di * 16 + l16;
                    size_t gidx = ((size_t)(b * SEQ + np)) * DIM + col;
                    out[gidx] = o[ch][di][r] * lr[r] + x[gidx];
                }
        }
    }
}

extern "C" void kernel_launch(void* const* d_in, const int* in_sizes, int n_in,
                              void* d_out, int out_size, void* d_ws, size_t ws_size,
                              hipStream_t stream) {
    const float* x  = (const float*)d_in[0];   // [2,2048,1024]
    const float* Wq = (const float*)d_in[1];   // [1024,3072]
    float* out = (float*)d_out;

    unsigned short* xb = (unsigned short*)d_ws;                  // [4096][1024]
    unsigned short* Wt = xb + (size_t)M_TOT * DIM;               // [3072][1024]
    unsigned short* Qw = Wt + (size_t)NQKV * DIM;                // [32][2048][64]
    unsigned short* Kw = Qw + (size_t)32 * SEQ * DHEAD;          // [32][2048][64]
    unsigned short* Vt = Kw + (size_t)32 * SEQ * DHEAD;          // [32][64][2048]

    prep_kernel<<<CAST_BLOCKS + TR_NB * (DIM / 64), 256, 0, stream>>>(x, xb, Wq, Wt);
    qkv_gemm_kernel<<<dim3(NQKV / 128, M_TOT / 128), 256, 0, stream>>>(xb, Wt, Qw, Kw, Vt);
    attn_kernel<<<(SEQ / 128) * 32, 512, 0, stream>>>(Qw, Kw, Vt, x, out);
}